// Round 9
// baseline (195.854 us; speedup 1.0000x reference)
//
#include <hip/hip_runtime.h>
#include <hip/hip_bf16.h>
#include <stdint.h>

// ---------------------------------------------------------------------------
// TripletLoss (batch-hard) on MI355X — R9: BM=256 (rt=4) to halve LDS reads.
// loss = mean over valid anchors of relu(hardest_pos - hardest_neg + 0.5)
// Full rectangular Gram via mfma_f32_16x16x32_bf16 on plain bf16 X.
// u-transform: acc init = -sq_j/2, so MFMA emits u = dot - sq_j/2 directly.
// d2 = sq_i - 2u is monotone DECREASING in u => hardest_pos = min u over
// same-label, hardest_neg = max u over diff-label; sq_i and sqrt folded in
// at the reduce. Diagonal excluded by value (self u = sq/2 -> d2 = 0; valid
// positive iff d2_pos > 1).
// B staged in LDS via global_load_lds(16B) + XOR slot swizzle (linear LDS
// dest, inverse-swizzled global src, swizzled ds_read_b128 -> conflict-free),
// double-buffered with plain __syncthreads (R8 showed fancy barriers = flat).
// R9 rationale: LDS-read volume = 4 waves x staged bytes ~ 1/BM; BM 128->256
// halves the dominant LDS-pipe time (~12 -> ~6-7 us/CU) and amortizes per-jj
// VALU overhead over 16 accum elements.
// ---------------------------------------------------------------------------

typedef __bf16 bf16x8 __attribute__((ext_vector_type(8)));
typedef float f32x4 __attribute__((ext_vector_type(4)));

constexpr int NB = 8192;     // batch
constexpr int ND = 128;      // dim
constexpr int SPLIT = 32;    // column splits (grid.y)
constexpr int JR = NB / SPLIT;          // 256 cols per block
constexpr int BN = 64;                  // cols per LDS tile
constexpr int NT = JR / BN;             // 4 tiles
constexpr int BM = 256;                 // rows per block (4 waves x 64)
constexpr int NRB = NB / BM;            // 32 row-blocks (grid 32x32 = 1024)

// workspace layout (bytes)
constexpr size_t OFF_XB  = 0;                                  // bf16 X [8192][128]
constexpr size_t OFF_SQ  = (size_t)NB * ND * 2;                // f32 [8192]
constexpr size_t OFF_LAB = OFF_SQ + (size_t)NB * 4;            // i32 [8192]
constexpr size_t OFF_HP  = OFF_LAB + (size_t)NB * 4;           // f32 [SPLIT][8192]
constexpr size_t OFF_HN  = OFF_HP + (size_t)SPLIT * NB * 4;    // f32 [SPLIT][8192]
constexpr size_t OFF_ACC = OFF_HN + (size_t)SPLIT * NB * 4;    // f32[2] + i32 cnt

__device__ __forceinline__ unsigned short f2bf(float f) {
  union { float f; uint32_t u; } c; c.f = f;
  uint32_t u = c.u;
  u += 0x7fffu + ((u >> 16) & 1u);   // RNE
  return (unsigned short)(u >> 16);
}

// ---- prep: fp32 -> bf16 X, row norms, labels, zero accumulators ------------
__global__ __launch_bounds__(256) void prep_kernel(
    const float* __restrict__ x, const int* __restrict__ labels,
    unsigned short* __restrict__ xb, float* __restrict__ sq,
    int* __restrict__ lab, float* __restrict__ acc, int* __restrict__ cnt) {
  if (blockIdx.x == 0 && threadIdx.x == 0) {
    acc[0] = 0.f;
    acc[1] = 0.f;
    *cnt = 0;
  }
  const int row = blockIdx.x * 8 + (threadIdx.x >> 5);
  const int sub = threadIdx.x & 31;
  const float4 v = *reinterpret_cast<const float4*>(x + (size_t)row * ND + sub * 4);
  ushort4 o;
  o.x = f2bf(v.x); o.y = f2bf(v.y); o.z = f2bf(v.z); o.w = f2bf(v.w);
  *reinterpret_cast<ushort4*>(xb + (size_t)row * ND + sub * 4) = o;
  float s = v.x * v.x + v.y * v.y + v.z * v.z + v.w * v.w;
#pragma unroll
  for (int m = 1; m < 32; m <<= 1) s += __shfl_xor(s, m);
  if (sub == 0) {
    sq[row] = s;
    lab[row] = labels[row];
  }
}

// ---- main: LDS-pipelined fused Gram + hardest-pos/neg mining ---------------
// Block = 256 rows x 256 cols, 4 waves x 64 rows (rt=4). A (X) in regs full-K.
// B tiles double-buffered in LDS, prefetch-next-while-compute.
__global__ __launch_bounds__(256, 3) void hard_kernel(
    const unsigned short* __restrict__ xb, const float* __restrict__ sq,
    const int* __restrict__ lab, float* __restrict__ hp_out,
    float* __restrict__ hn_out) {
  __shared__ __align__(16) char smem[2][BN * ND * 2];  // 2 x 16 KB
  __shared__ float sqh[JR];   // 1 KB, holds -sq/2
  __shared__ int labl[JR];    // 1 KB
  const int tid = threadIdx.x;
  const int lane = tid & 63;
  const int w = tid >> 6;
  const int c16 = lane & 15;  // A-row / B-col / C-col within 16
  const int g4 = lane >> 4;   // k-group; C-row group
  const int rowbase = blockIdx.x * BM + w * 64;
  const int colbase = blockIdx.y * JR;

  auto stage = [&](int buf, int tile) {  // stage 64-col B tile (4 vmem ops)
    const char* gbase = reinterpret_cast<const char*>(xb) +
                        ((size_t)(colbase + tile * BN)) * (ND * 2);
#pragma unroll
    for (int rnd = 0; rnd < 4; ++rnd) {
      const int L = rnd * 4096 + tid * 16;        // linear LDS byte
      const int slot = (L >> 4) & 15;             // 16B slot within 256B row
      const int col = L >> 8;                     // tile row (= gram col)
      const int src = (L & ~0xF0) | ((slot ^ (col & 15)) << 4);
      __builtin_amdgcn_global_load_lds(
          (const __attribute__((address_space(1))) unsigned int*)(gbase + src),
          (__attribute__((address_space(3))) unsigned int*)(&smem[buf][L]),
          16, 0, 0);
    }
  };

  stage(0, 0);
  {  // stage -sq/2 and labels for this block's 256 cols
    sqh[tid] = -0.5f * sq[colbase + tid];
    labl[tid] = lab[colbase + tid];
  }

  // A fragments (X): lane holds row rowbase + rt*16 + c16, k = kk*32+g4*8+i
  bf16x8 afrag[4][4];
#pragma unroll
  for (int rt = 0; rt < 4; ++rt) {
    const unsigned short* ap =
        xb + ((size_t)(rowbase + rt * 16 + c16)) * ND + g4 * 8;
#pragma unroll
    for (int kk = 0; kk < 4; ++kk)
      afrag[rt][kk] = *reinterpret_cast<const bf16x8*>(ap + kk * 32);
  }
  // labels of the C rows this lane owns: row = rt*16 + g4*4 + rr
  int labr[4][4];
#pragma unroll
  for (int rt = 0; rt < 4; ++rt)
#pragma unroll
    for (int rr = 0; rr < 4; ++rr)
      labr[rt][rr] = lab[rowbase + rt * 16 + g4 * 4 + rr];

  // running mins/maxs in u-space: hpu = min u over same, hnu = max u over diff
  float hpu[4][4], hnu[4][4];
#pragma unroll
  for (int rt = 0; rt < 4; ++rt)
#pragma unroll
    for (int rr = 0; rr < 4; ++rr) {
      hpu[rt][rr] = __builtin_inff();
      hnu[rt][rr] = -__builtin_inff();
    }

  __syncthreads();  // tile 0 + sqh/labl ready

  for (int t = 0; t < NT; ++t) {
    if (t + 1 < NT) stage((t + 1) & 1, t + 1);  // prefetch next tile
    const char* sb = smem[t & 1];
#pragma unroll
    for (int jj = 0; jj < 4; ++jj) {
      const int colL = jj * 16 + c16;        // col within 64-tile
      const int jidx = t * BN + colL;        // col within 256-range
      const float sqc = sqh[jidx];           // -sq_j/2
      const int labc = labl[jidx];

      bf16x8 bfrag[4];
#pragma unroll
      for (int kk = 0; kk < 4; ++kk) {
        const int kbyte = kk * 64 + g4 * 16;
        const int a = colL * 256 + (kbyte ^ (c16 << 4));  // swizzled read
        bfrag[kk] = *reinterpret_cast<const bf16x8*>(sb + a);
      }

      // acc starts at -sq_j/2 -> MFMA emits u = dot - sq_j/2
      f32x4 acc[4];
#pragma unroll
      for (int rt = 0; rt < 4; ++rt) acc[rt] = (f32x4){sqc, sqc, sqc, sqc};
      __builtin_amdgcn_s_setprio(1);
#pragma unroll
      for (int kk = 0; kk < 4; ++kk)
#pragma unroll
        for (int rt = 0; rt < 4; ++rt)
          acc[rt] = __builtin_amdgcn_mfma_f32_16x16x32_bf16(
              afrag[rt][kk], bfrag[kk], acc[rt], 0, 0, 0);
      __builtin_amdgcn_s_setprio(0);

      // epilogue: d2 monotone-decreasing in u => min for pos, max for neg
#pragma unroll
      for (int rt = 0; rt < 4; ++rt)
#pragma unroll
        for (int rr = 0; rr < 4; ++rr) {
          const float u = acc[rt][rr];
          const bool same = (labc == labr[rt][rr]);
          hpu[rt][rr] = fminf(hpu[rt][rr], same ? u : __builtin_inff());
          hnu[rt][rr] = fmaxf(hnu[rt][rr], same ? -__builtin_inff() : u);
        }
    }
    __syncthreads();
  }

  // combine the 16 column-lanes of each C row, write per-split partials
#pragma unroll
  for (int rt = 0; rt < 4; ++rt)
#pragma unroll
    for (int rr = 0; rr < 4; ++rr) {
      float p = hpu[rt][rr], n = hnu[rt][rr];
#pragma unroll
      for (int m = 1; m <= 8; m <<= 1) {
        p = fminf(p, __shfl_xor(p, m));
        n = fmaxf(n, __shfl_xor(n, m));
      }
      if (c16 == 0) {
        const int rg = rowbase + rt * 16 + g4 * 4 + rr;
        hp_out[(size_t)blockIdx.y * NB + rg] = p;   // min-u partial
        hn_out[(size_t)blockIdx.y * NB + rg] = n;   // max-u partial
      }
    }
}

// ---- reduce: combine splits, per-anchor loss, global sum, fused finalize ---
__global__ __launch_bounds__(256) void reduce_kernel(
    const float* __restrict__ hp, const float* __restrict__ hn,
    const float* __restrict__ sq, float* __restrict__ acc,
    int* __restrict__ cnt_done, float* __restrict__ out) {
  const int a = blockIdx.x * 256 + threadIdx.x;
  float p = __builtin_inff(), n = -__builtin_inff();
#pragma unroll 8
  for (int s = 0; s < SPLIT; ++s) {
    p = fminf(p, hp[(size_t)s * NB + a]);
    n = fmaxf(n, hn[(size_t)s * NB + a]);
  }
  const float sqa = sq[a];
  const float d2p = fmaxf(fmaf(-2.f, p, sqa), 0.f);  // sq_a - 2*min_u
  const float d2n = fmaxf(fmaf(-2.f, n, sqa), 0.f);  // sq_a - 2*max_u
  // d2p > 1: a real positive exists (self gives u = sq/2 -> d2 = 0; true
  // positive d2 >> 64 for this data). n > -1e37: a negative exists.
  const bool valid = (d2p > 1.0f) && (n > -1e37f);
  float loss = valid ? fmaxf(sqrtf(d2p) - sqrtf(d2n) + 0.5f, 0.f) : 0.f;
  float c = valid ? 1.f : 0.f;
#pragma unroll
  for (int m = 1; m < 64; m <<= 1) {
    loss += __shfl_xor(loss, m);
    c += __shfl_xor(c, m);
  }
  __shared__ float ls[4], cs[4];
  const int w = threadIdx.x >> 6, lane = threadIdx.x & 63;
  if (lane == 0) { ls[w] = loss; cs[w] = c; }
  __syncthreads();
  if (threadIdx.x == 0) {
    atomicAdd(&acc[0], ls[0] + ls[1] + ls[2] + ls[3]);
    atomicAdd(&acc[1], cs[0] + cs[1] + cs[2] + cs[3]);
    __threadfence();
    const int old = atomicAdd(cnt_done, 1);
    if (old == (NB / 256) - 1) {  // last block finalizes
      const float l = atomicAdd(&acc[0], 0.0f);
      const float nvalid = atomicAdd(&acc[1], 0.0f);
      out[0] = l / fmaxf(nvalid, 1.f);
    }
  }
}

// ---------------------------------------------------------------------------
extern "C" void kernel_launch(void* const* d_in, const int* in_sizes, int n_in,
                              void* d_out, int out_size, void* d_ws,
                              size_t ws_size, hipStream_t stream) {
  const float* x = (const float*)d_in[0];
  const int* labels = (const int*)d_in[1];
  char* ws = (char*)d_ws;
  unsigned short* xb = (unsigned short*)(ws + OFF_XB);
  float* sq = (float*)(ws + OFF_SQ);
  int* lab = (int*)(ws + OFF_LAB);
  float* hp = (float*)(ws + OFF_HP);
  float* hn = (float*)(ws + OFF_HN);
  float* acc = (float*)(ws + OFF_ACC);
  int* cnt = (int*)(ws + OFF_ACC + 8);

  prep_kernel<<<NB / 8, 256, 0, stream>>>(x, labels, xb, sq, lab, acc, cnt);
  hard_kernel<<<dim3(NRB, SPLIT), 256, 0, stream>>>(xb, sq, lab, hp, hn);
  reduce_kernel<<<NB / 256, 256, 0, stream>>>(hp, hn, sq, acc, cnt,
                                              (float*)d_out);
}

// Round 10
// 94.287 us; speedup vs baseline: 2.0772x; 2.0772x over previous
//
#include <hip/hip_runtime.h>
#include <hip/hip_bf16.h>
#include <stdint.h>

// ---------------------------------------------------------------------------
// TripletLoss (batch-hard) on MI355X — R10: R9 structure, register cap fixed.
// loss = mean over valid anchors of relu(hardest_pos - hardest_neg + 0.5)
// Full rectangular Gram via mfma_f32_16x16x32_bf16 on plain bf16 X.
// u-transform: acc init = -sq_j/2, so MFMA emits u = dot - sq_j/2 directly.
// d2 = sq_i - 2u is monotone DECREASING in u => hardest_pos = min u over
// same-label, hardest_neg = max u over diff-label; sq_i and sqrt folded in
// at the reduce. Diagonal excluded by value (self u = sq/2 -> d2 = 0; valid
// positive iff d2_pos > 1).
// B staged in LDS via global_load_lds(16B) + XOR slot swizzle (linear LDS
// dest, inverse-swizzled global src, swizzled ds_read_b128 -> conflict-free),
// double-buffered with plain __syncthreads.
// R10 fix: R9's __launch_bounds__(256,3) capped VGPR at ~168 < ~170+temps
// live set -> compiler spilled persistent arrays to scratch (VGPR_Count 84,
// 200 MB WRITE_SIZE, 0.9% occupancy). (256,2) gives the allocator 256 regs;
// live ~160 fits, occupancy ~3 waves/SIMD via VGPR. BM=256 (64 rows/wave)
// halves LDS-read volume vs BM=128 (reads scale as 1/BM).
// ---------------------------------------------------------------------------

typedef __bf16 bf16x8 __attribute__((ext_vector_type(8)));
typedef float f32x4 __attribute__((ext_vector_type(4)));

constexpr int NB = 8192;     // batch
constexpr int ND = 128;      // dim
constexpr int SPLIT = 32;    // column splits (grid.y)
constexpr int JR = NB / SPLIT;          // 256 cols per block
constexpr int BN = 64;                  // cols per LDS tile
constexpr int NT = JR / BN;             // 4 tiles
constexpr int BM = 256;                 // rows per block (4 waves x 64)
constexpr int NRB = NB / BM;            // 32 row-blocks (grid 32x32 = 1024)

// workspace layout (bytes)
constexpr size_t OFF_XB  = 0;                                  // bf16 X [8192][128]
constexpr size_t OFF_SQ  = (size_t)NB * ND * 2;                // f32 [8192]
constexpr size_t OFF_LAB = OFF_SQ + (size_t)NB * 4;            // i32 [8192]
constexpr size_t OFF_HP  = OFF_LAB + (size_t)NB * 4;           // f32 [SPLIT][8192]
constexpr size_t OFF_HN  = OFF_HP + (size_t)SPLIT * NB * 4;    // f32 [SPLIT][8192]
constexpr size_t OFF_ACC = OFF_HN + (size_t)SPLIT * NB * 4;    // f32[2] + i32 cnt

__device__ __forceinline__ unsigned short f2bf(float f) {
  union { float f; uint32_t u; } c; c.f = f;
  uint32_t u = c.u;
  u += 0x7fffu + ((u >> 16) & 1u);   // RNE
  return (unsigned short)(u >> 16);
}

// ---- prep: fp32 -> bf16 X, row norms, labels, zero accumulators ------------
__global__ __launch_bounds__(256) void prep_kernel(
    const float* __restrict__ x, const int* __restrict__ labels,
    unsigned short* __restrict__ xb, float* __restrict__ sq,
    int* __restrict__ lab, float* __restrict__ acc, int* __restrict__ cnt) {
  if (blockIdx.x == 0 && threadIdx.x == 0) {
    acc[0] = 0.f;
    acc[1] = 0.f;
    *cnt = 0;
  }
  const int row = blockIdx.x * 8 + (threadIdx.x >> 5);
  const int sub = threadIdx.x & 31;
  const float4 v = *reinterpret_cast<const float4*>(x + (size_t)row * ND + sub * 4);
  ushort4 o;
  o.x = f2bf(v.x); o.y = f2bf(v.y); o.z = f2bf(v.z); o.w = f2bf(v.w);
  *reinterpret_cast<ushort4*>(xb + (size_t)row * ND + sub * 4) = o;
  float s = v.x * v.x + v.y * v.y + v.z * v.z + v.w * v.w;
#pragma unroll
  for (int m = 1; m < 32; m <<= 1) s += __shfl_xor(s, m);
  if (sub == 0) {
    sq[row] = s;
    lab[row] = labels[row];
  }
}

// ---- main: LDS-pipelined fused Gram + hardest-pos/neg mining ---------------
// Block = 256 rows x 256 cols, 4 waves x 64 rows (rt=4). A (X) in regs full-K.
// B tiles double-buffered in LDS, prefetch-next-while-compute.
__global__ __launch_bounds__(256, 2) void hard_kernel(
    const unsigned short* __restrict__ xb, const float* __restrict__ sq,
    const int* __restrict__ lab, float* __restrict__ hp_out,
    float* __restrict__ hn_out) {
  __shared__ __align__(16) char smem[2][BN * ND * 2];  // 2 x 16 KB
  __shared__ float sqh[JR];   // 1 KB, holds -sq/2
  __shared__ int labl[JR];    // 1 KB
  const int tid = threadIdx.x;
  const int lane = tid & 63;
  const int w = tid >> 6;
  const int c16 = lane & 15;  // A-row / B-col / C-col within 16
  const int g4 = lane >> 4;   // k-group; C-row group
  const int rowbase = blockIdx.x * BM + w * 64;
  const int colbase = blockIdx.y * JR;

  auto stage = [&](int buf, int tile) {  // stage 64-col B tile (4 vmem ops)
    const char* gbase = reinterpret_cast<const char*>(xb) +
                        ((size_t)(colbase + tile * BN)) * (ND * 2);
#pragma unroll
    for (int rnd = 0; rnd < 4; ++rnd) {
      const int L = rnd * 4096 + tid * 16;        // linear LDS byte
      const int slot = (L >> 4) & 15;             // 16B slot within 256B row
      const int col = L >> 8;                     // tile row (= gram col)
      const int src = (L & ~0xF0) | ((slot ^ (col & 15)) << 4);
      __builtin_amdgcn_global_load_lds(
          (const __attribute__((address_space(1))) unsigned int*)(gbase + src),
          (__attribute__((address_space(3))) unsigned int*)(&smem[buf][L]),
          16, 0, 0);
    }
  };

  stage(0, 0);
  {  // stage -sq/2 and labels for this block's 256 cols
    sqh[tid] = -0.5f * sq[colbase + tid];
    labl[tid] = lab[colbase + tid];
  }

  // A fragments (X): lane holds row rowbase + rt*16 + c16, k = kk*32+g4*8+i
  bf16x8 afrag[4][4];
#pragma unroll
  for (int rt = 0; rt < 4; ++rt) {
    const unsigned short* ap =
        xb + ((size_t)(rowbase + rt * 16 + c16)) * ND + g4 * 8;
#pragma unroll
    for (int kk = 0; kk < 4; ++kk)
      afrag[rt][kk] = *reinterpret_cast<const bf16x8*>(ap + kk * 32);
  }
  // labels of the C rows this lane owns: row = rt*16 + g4*4 + rr
  int labr[4][4];
#pragma unroll
  for (int rt = 0; rt < 4; ++rt)
#pragma unroll
    for (int rr = 0; rr < 4; ++rr)
      labr[rt][rr] = lab[rowbase + rt * 16 + g4 * 4 + rr];

  // running mins/maxs in u-space: hpu = min u over same, hnu = max u over diff
  float hpu[4][4], hnu[4][4];
#pragma unroll
  for (int rt = 0; rt < 4; ++rt)
#pragma unroll
    for (int rr = 0; rr < 4; ++rr) {
      hpu[rt][rr] = __builtin_inff();
      hnu[rt][rr] = -__builtin_inff();
    }

  __syncthreads();  // tile 0 + sqh/labl ready

  for (int t = 0; t < NT; ++t) {
    if (t + 1 < NT) stage((t + 1) & 1, t + 1);  // prefetch next tile
    const char* sb = smem[t & 1];
#pragma unroll
    for (int jj = 0; jj < 4; ++jj) {
      const int colL = jj * 16 + c16;        // col within 64-tile
      const int jidx = t * BN + colL;        // col within 256-range
      const float sqc = sqh[jidx];           // -sq_j/2
      const int labc = labl[jidx];

      bf16x8 bfrag[4];
#pragma unroll
      for (int kk = 0; kk < 4; ++kk) {
        const int kbyte = kk * 64 + g4 * 16;
        const int a = colL * 256 + (kbyte ^ (c16 << 4));  // swizzled read
        bfrag[kk] = *reinterpret_cast<const bf16x8*>(sb + a);
      }

      // acc starts at -sq_j/2 -> MFMA emits u = dot - sq_j/2
      f32x4 acc[4];
#pragma unroll
      for (int rt = 0; rt < 4; ++rt) acc[rt] = (f32x4){sqc, sqc, sqc, sqc};
      __builtin_amdgcn_s_setprio(1);
#pragma unroll
      for (int kk = 0; kk < 4; ++kk)
#pragma unroll
        for (int rt = 0; rt < 4; ++rt)
          acc[rt] = __builtin_amdgcn_mfma_f32_16x16x32_bf16(
              afrag[rt][kk], bfrag[kk], acc[rt], 0, 0, 0);
      __builtin_amdgcn_s_setprio(0);

      // epilogue: d2 monotone-decreasing in u => min for pos, max for neg
#pragma unroll
      for (int rt = 0; rt < 4; ++rt)
#pragma unroll
        for (int rr = 0; rr < 4; ++rr) {
          const float u = acc[rt][rr];
          const bool same = (labc == labr[rt][rr]);
          hpu[rt][rr] = fminf(hpu[rt][rr], same ? u : __builtin_inff());
          hnu[rt][rr] = fmaxf(hnu[rt][rr], same ? -__builtin_inff() : u);
        }
    }
    __syncthreads();
  }

  // combine the 16 column-lanes of each C row, write per-split partials
#pragma unroll
  for (int rt = 0; rt < 4; ++rt)
#pragma unroll
    for (int rr = 0; rr < 4; ++rr) {
      float p = hpu[rt][rr], n = hnu[rt][rr];
#pragma unroll
      for (int m = 1; m <= 8; m <<= 1) {
        p = fminf(p, __shfl_xor(p, m));
        n = fmaxf(n, __shfl_xor(n, m));
      }
      if (c16 == 0) {
        const int rg = rowbase + rt * 16 + g4 * 4 + rr;
        hp_out[(size_t)blockIdx.y * NB + rg] = p;   // min-u partial
        hn_out[(size_t)blockIdx.y * NB + rg] = n;   // max-u partial
      }
    }
}

// ---- reduce: combine splits, per-anchor loss, global sum, fused finalize ---
__global__ __launch_bounds__(256) void reduce_kernel(
    const float* __restrict__ hp, const float* __restrict__ hn,
    const float* __restrict__ sq, float* __restrict__ acc,
    int* __restrict__ cnt_done, float* __restrict__ out) {
  const int a = blockIdx.x * 256 + threadIdx.x;
  float p = __builtin_inff(), n = -__builtin_inff();
#pragma unroll 8
  for (int s = 0; s < SPLIT; ++s) {
    p = fminf(p, hp[(size_t)s * NB + a]);
    n = fmaxf(n, hn[(size_t)s * NB + a]);
  }
  const float sqa = sq[a];
  const float d2p = fmaxf(fmaf(-2.f, p, sqa), 0.f);  // sq_a - 2*min_u
  const float d2n = fmaxf(fmaf(-2.f, n, sqa), 0.f);  // sq_a - 2*max_u
  // d2p > 1: a real positive exists (self gives u = sq/2 -> d2 = 0; true
  // positive d2 >> 64 for this data). n > -1e37: a negative exists.
  const bool valid = (d2p > 1.0f) && (n > -1e37f);
  float loss = valid ? fmaxf(sqrtf(d2p) - sqrtf(d2n) + 0.5f, 0.f) : 0.f;
  float c = valid ? 1.f : 0.f;
#pragma unroll
  for (int m = 1; m < 64; m <<= 1) {
    loss += __shfl_xor(loss, m);
    c += __shfl_xor(c, m);
  }
  __shared__ float ls[4], cs[4];
  const int w = threadIdx.x >> 6, lane = threadIdx.x & 63;
  if (lane == 0) { ls[w] = loss; cs[w] = c; }
  __syncthreads();
  if (threadIdx.x == 0) {
    atomicAdd(&acc[0], ls[0] + ls[1] + ls[2] + ls[3]);
    atomicAdd(&acc[1], cs[0] + cs[1] + cs[2] + cs[3]);
    __threadfence();
    const int old = atomicAdd(cnt_done, 1);
    if (old == (NB / 256) - 1) {  // last block finalizes
      const float l = atomicAdd(&acc[0], 0.0f);
      const float nvalid = atomicAdd(&acc[1], 0.0f);
      out[0] = l / fmaxf(nvalid, 1.f);
    }
  }
}

// ---------------------------------------------------------------------------
extern "C" void kernel_launch(void* const* d_in, const int* in_sizes, int n_in,
                              void* d_out, int out_size, void* d_ws,
                              size_t ws_size, hipStream_t stream) {
  const float* x = (const float*)d_in[0];
  const int* labels = (const int*)d_in[1];
  char* ws = (char*)d_ws;
  unsigned short* xb = (unsigned short*)(ws + OFF_XB);
  float* sq = (float*)(ws + OFF_SQ);
  int* lab = (int*)(ws + OFF_LAB);
  float* hp = (float*)(ws + OFF_HP);
  float* hn = (float*)(ws + OFF_HN);
  float* acc = (float*)(ws + OFF_ACC);
  int* cnt = (int*)(ws + OFF_ACC + 8);

  prep_kernel<<<NB / 8, 256, 0, stream>>>(x, labels, xb, sq, lab, acc, cnt);
  hard_kernel<<<dim3(NRB, SPLIT), 256, 0, stream>>>(xb, sq, lab, hp, hn);
  reduce_kernel<<<NB / 256, 256, 0, stream>>>(hp, hn, sq, acc, cnt,
                                              (float*)d_out);
}